// Round 3
// baseline (2744.539 us; speedup 1.0000x reference)
//
#include <hip/hip_runtime.h>

// ChebConv(K=3) x3 on MI355X.  Round 2 (resubmit after broker timeout).
// SpMM: column-chunked (32 cols/chunk -> 3.2 MB table slice fits per-XCD L2),
//       chunk-major launch order so all in-flight blocks share a chunk.
// GEMM: 128x128 bf16 MFMA tile; nt-fastest + bijective XCD swizzle (A-panel L2
//       reuse); st-style XOR LDS swizzle (pre-swizzled global src + swizzled
//       ds_read; linear global_load_lds dest).

typedef unsigned short u16;
typedef __attribute__((ext_vector_type(8))) short s16x8;
typedef __attribute__((ext_vector_type(4))) float f32x4;
typedef __attribute__((ext_vector_type(8))) unsigned short u16x8;
typedef __attribute__((ext_vector_type(4))) unsigned short u16x4;

__device__ __forceinline__ float b2f(u16 u) {
  union { unsigned int i; float f; } x; x.i = ((unsigned int)u) << 16; return x.f;
}
__device__ __forceinline__ u16 f2b(float f) {  // round-to-nearest-even
  union { float f; unsigned int i; } x; x.f = f;
  unsigned int r = x.i + 0x7fffu + ((x.i >> 16) & 1u);
  return (u16)(r >> 16);
}

typedef __attribute__((address_space(1))) unsigned int gu32_t;
typedef __attribute__((address_space(3))) unsigned int lu32_t;
__device__ __forceinline__ void gload16(const void* g, void* l) {
  __builtin_amdgcn_global_load_lds((const gu32_t*)g, (lu32_t*)l, 16, 0, 0);
}

// ----------------- CSR build -----------------
__global__ void k_zero_i32(int* p, int n) {
  int t = blockIdx.x * 256 + threadIdx.x;
  if (t < n) p[t] = 0;
}

__global__ void k_hist(const int* __restrict__ ei, int* __restrict__ cnt, int E) {
  int e = blockIdx.x * 256 + threadIdx.x;
  if (e < E) atomicAdd(&cnt[ei[E + e]], 1);  // ei[1][e] = dst
}

__global__ void k_dis(const int* __restrict__ cnt, float* __restrict__ dis, int N) {
  int t = blockIdx.x * 256 + threadIdx.x;
  if (t < N) dis[t] = cnt[t] > 0 ? rsqrtf((float)cnt[t]) : 0.f;
}

__global__ void k_scan1(const int* __restrict__ cnt, int* __restrict__ part, int N) {
  __shared__ int s[256];
  int t = threadIdx.x, idx = blockIdx.x * 256 + t;
  s[t] = idx < N ? cnt[idx] : 0;
  __syncthreads();
  for (int o = 128; o > 0; o >>= 1) {
    if (t < o) s[t] += s[t + o];
    __syncthreads();
  }
  if (t == 0) part[blockIdx.x] = s[0];
}

__global__ void k_scan2(int* part, int nb, int* csroff, int N, int E) {
  if (threadIdx.x == 0 && blockIdx.x == 0) {
    int run = 0;
    for (int b = 0; b < nb; ++b) { int v = part[b]; part[b] = run; run += v; }
    csroff[N] = E;
  }
}

__global__ void k_scan3(const int* __restrict__ cnt, const int* __restrict__ part,
                        int* __restrict__ csroff, int* __restrict__ cursor, int N) {
  __shared__ int s[256];
  int t = threadIdx.x, idx = blockIdx.x * 256 + t;
  int v = idx < N ? cnt[idx] : 0;
  s[t] = v;
  __syncthreads();
  for (int o = 1; o < 256; o <<= 1) {
    int add = t >= o ? s[t - o] : 0;
    __syncthreads();
    s[t] += add;
    __syncthreads();
  }
  if (idx < N) {
    int ex = part[blockIdx.x] + s[t] - v;
    csroff[idx] = ex;
    cursor[idx] = ex;
  }
}

__global__ void k_scatter(const int* __restrict__ ei, int* __restrict__ cursor,
                          int* __restrict__ csrsrc, int E) {
  int e = blockIdx.x * 256 + threadIdx.x;
  if (e >= E) return;
  int s = ei[e];          // src
  int d = ei[E + e];      // dst
  int pos = atomicAdd(&cursor[d], 1);
  csrsrc[pos] = s;
}

// ----------------- converts -----------------
__global__ void k_convx(const float* __restrict__ x, u16* __restrict__ C, int N, int NPAD) {
  int t = blockIdx.x * 256 + threadIdx.x;
  int row = t >> 6;
  if (row >= NPAD) return;
  int c0 = (t & 63) * 8;
  u16x8 o;
  if (row < N) {
    const float4* p = (const float4*)(x + (size_t)row * 512 + c0);
    float4 a = p[0], b = p[1];
    o[0] = f2b(a.x); o[1] = f2b(a.y); o[2] = f2b(a.z); o[3] = f2b(a.w);
    o[4] = f2b(b.x); o[5] = f2b(b.y); o[6] = f2b(b.z); o[7] = f2b(b.w);
  } else {
#pragma unroll
    for (int j = 0; j < 8; ++j) o[j] = 0;
  }
  *(u16x8*)(C + (size_t)row * 1536 + c0) = o;
}

// Wb[n][ck*Kpad + k] = W[ck][k][n] (bf16, zero-padded)
__global__ void k_convw(const float* __restrict__ W, u16* __restrict__ Wb,
                        int Fin, int Kpad, int Nout) {
  int n = blockIdx.x;
  int ldw = 3 * Kpad;
  for (int kk = threadIdx.x; kk < ldw; kk += 256) {
    int ck = kk / Kpad, k = kk - ck * Kpad;
    float v = (k < Fin && n < Nout) ? W[((size_t)ck * Fin + k) * Nout + n] : 0.f;
    Wb[(size_t)n * ldw + kk] = f2b(v);
  }
}

// ----------------- SpMM, column-chunked -----------------
// chunk = 32 cols (table slice 50000*32*2B = 3.2 MB < 4 MB per-XCD L2).
// block: 256 threads = 32 rows x 8 lanes (4 cols/lane).
// grid: (ceil(N/32), Kpad/32) -- chunk (y) slowest => in-flight blocks share chunk.
// O[r] = alpha * Lhat(G)[r] - (Hs ? Hs[r] : 0);  Lhat = -disd * sum(dis[s]*G[s]) + diag.
__global__ __launch_bounds__(256) void spmm_c(
    const u16* __restrict__ G, const u16* __restrict__ Hs, u16* __restrict__ O, int ld,
    const int* __restrict__ off, const int* __restrict__ srcs,
    const float* __restrict__ dis, float alpha, int N) {
  const int r = blockIdx.x * 32 + (threadIdx.x >> 3);
  if (r >= N) return;
  const int cc = blockIdx.y * 32 + (threadIdx.x & 7) * 4;
  const u16* __restrict__ Gc = G + cc;
  float acc[4] = {0.f, 0.f, 0.f, 0.f};
  int e = off[r];
  const int e1 = off[r + 1];
  for (; e + 2 <= e1; e += 2) {  // unroll x2 for outstanding gathers
    const int s0 = srcs[e], s1 = srcs[e + 1];
    const float w0 = dis[s0], w1 = dis[s1];
    const u16x4 v0 = *(const u16x4*)(Gc + (size_t)s0 * ld);
    const u16x4 v1 = *(const u16x4*)(Gc + (size_t)s1 * ld);
#pragma unroll
    for (int j = 0; j < 4; ++j) acc[j] += w0 * b2f(v0[j]) + w1 * b2f(v1[j]);
  }
  if (e < e1) {
    const int s0 = srcs[e];
    const float w0 = dis[s0];
    const u16x4 v0 = *(const u16x4*)(Gc + (size_t)s0 * ld);
#pragma unroll
    for (int j = 0; j < 4; ++j) acc[j] += w0 * b2f(v0[j]);
  }
  const float disd = dis[r];
  float lap[4];
#pragma unroll
  for (int j = 0; j < 4; ++j) lap[j] = -disd * acc[j];
  if (disd == 0.f) {  // isolated node: diag_w = -1
    const u16x4 v = *(const u16x4*)(Gc + (size_t)r * ld);
#pragma unroll
    for (int j = 0; j < 4; ++j) lap[j] -= b2f(v[j]);
  }
  u16x4 o;
  if (Hs) {
    const u16x4 h = *(const u16x4*)(Hs + (size_t)r * ld + cc);
#pragma unroll
    for (int j = 0; j < 4; ++j) o[j] = f2b(alpha * lap[j] - b2f(h[j]));
  } else {
#pragma unroll
    for (int j = 0; j < 4; ++j) o[j] = f2b(lap[j]);
  }
  *(u16x4*)(O + (size_t)r * ld + cc) = o;
}

// ----------------- GEMM: C = relu(A @ B^T + bias) -----------------
// A: [Mpad][lda] bf16 row-major; B: [Npad][ldb] bf16 row-major (row n = col n of W).
// 128x128 tile, BK=64, 4 waves (2x2), 16x16x32 MFMA, global_load_lds staging.
// 1-D grid = MT*NT blocks; bijective XCD swizzle (m204), nt fastest within wg.
// LDS XOR swizzle: linear gload_lds dest + pre-swizzled global src + XOR'd read.
template <typename OUTT>
__global__ __launch_bounds__(256) void gemm_k(
    const u16* __restrict__ A, int lda,
    const u16* __restrict__ B, int ldb,
    const float* __restrict__ bias,
    OUTT* __restrict__ C, int ldc,
    int K, int Nout, int Nrows, int NT) {
  __shared__ u16 As[128 * 64];
  __shared__ u16 Bs[128 * 64];
  const int tid = threadIdx.x;
  const int w = tid >> 6, l = tid & 63;

  // bijective XCD swizzle: contiguous logical span per XCD; nt-minor.
  const int nwg = gridDim.x;
  const int q = nwg >> 3, r8 = nwg & 7;
  const int xcd = blockIdx.x & 7, idx = blockIdx.x >> 3;
  const int wg = (xcd < r8 ? xcd * (q + 1) : r8 * (q + 1) + (xcd - r8) * q) + idx;
  const int m0 = (wg / NT) * 128, n0 = (wg % NT) * 128;

  // staging: lane covers 16B; LDS dest linear (c*2048 + w*512 + l*8 u16).
  // source col pre-swizzled: granule (l&7) ^ (row&7), row&7 == l>>3.
  const int srow = w * 8 + (l >> 3);
  const int scol = ((l & 7) ^ (l >> 3)) * 8;
  const u16* ga = A + (size_t)m0 * lda + scol;
  const u16* gb = B + (size_t)n0 * ldb + scol;
  u16* lAs = &As[w * 512];
  u16* lBs = &Bs[w * 512];

  f32x4 acc[4][4];
#pragma unroll
  for (int m = 0; m < 4; ++m)
#pragma unroll
    for (int n = 0; n < 4; ++n) acc[m][n] = (f32x4){0.f, 0.f, 0.f, 0.f};

  const int wr = (w >> 1) * 64, wc = (w & 1) * 64;
  const int tr = l & 15, tg = l >> 4;
  const int rx = tr & 7;  // read-row XOR key (row&7 == tr&7)

  for (int k0 = 0; k0 < K; k0 += 64) {
    __syncthreads();
#pragma unroll
    for (int c = 0; c < 4; ++c) {
      gload16(ga + (size_t)(srow + c * 32) * lda + k0, lAs + c * 2048);
      gload16(gb + (size_t)(srow + c * 32) * ldb + k0, lBs + c * 2048);
    }
    __syncthreads();
#pragma unroll
    for (int kk = 0; kk < 64; kk += 32) {
      s16x8 af[4], bf[4];
#pragma unroll
      for (int m = 0; m < 4; ++m)
        af[m] = *(const s16x8*)&As[(wr + m * 16 + tr) * 64 + ((((kk >> 3) + tg) ^ rx) * 8)];
#pragma unroll
      for (int n = 0; n < 4; ++n)
        bf[n] = *(const s16x8*)&Bs[(wc + n * 16 + tr) * 64 + ((((kk >> 3) + tg) ^ rx) * 8)];
#pragma unroll
      for (int m = 0; m < 4; ++m)
#pragma unroll
        for (int n = 0; n < 4; ++n)
          acc[m][n] = __builtin_amdgcn_mfma_f32_16x16x32_bf16(af[m], bf[n], acc[m][n], 0, 0, 0);
    }
  }

  // epilogue: bias + relu; C/D layout: col = lane&15, row = (lane>>4)*4 + j
#pragma unroll
  for (int m = 0; m < 4; ++m) {
    const int gr0 = m0 + wr + m * 16 + tg * 4;
#pragma unroll
    for (int n = 0; n < 4; ++n) {
      const int gc = n0 + wc + n * 16 + tr;
      const float bv = (gc < Nout) ? bias[gc] : 0.f;
#pragma unroll
      for (int j = 0; j < 4; ++j) {
        float v = acc[m][n][j] + bv;
        v = v > 0.f ? v : 0.f;
        if constexpr (sizeof(OUTT) == 2) {
          // bf16 out: pad cols MUST be zero (they feed next layer's K)
          C[(size_t)(gr0 + j) * ldc + gc] = (gc < Nout) ? f2b(v) : (u16)0;
        } else {
          if (gr0 + j < Nrows && gc < Nout)
            C[(size_t)(gr0 + j) * ldc + gc] = v;
        }
      }
    }
  }
}

// ----------------- launch -----------------
extern "C" void kernel_launch(void* const* d_in, const int* in_sizes, int n_in,
                              void* d_out, int out_size, void* d_ws, size_t ws_size,
                              hipStream_t stream) {
  const float* x = (const float*)d_in[0];
  const int* ei = (const int*)d_in[1];
  const float* w1 = (const float*)d_in[2];
  const float* b1 = (const float*)d_in[3];
  const float* w2 = (const float*)d_in[4];
  const float* b2 = (const float*)d_in[5];
  const float* w3 = (const float*)d_in[6];
  const float* b3 = (const float*)d_in[7];
  float* out = (float*)d_out;

  const int N = in_sizes[0] / 512;      // 50000
  const int E = in_sizes[1] / 2;        // 1600000
  const int NPAD = ((N + 127) / 128) * 128;  // 50048
  const int NB = (N + 255) / 256;
  const int EB = (E + 255) / 256;
  const int MT = NPAD / 128;            // 391 M-tiles

  char* ws = (char*)d_ws;
  size_t o = 0;
  auto alloc = [&](size_t b) -> void* {
    void* p = ws + o;
    o = (o + b + 255) & ~(size_t)255;
    return p;
  };
  int* cnt = (int*)alloc((size_t)N * 4);
  float* dis = (float*)alloc((size_t)N * 4);
  int* csroff = (int*)alloc((size_t)(N + 1) * 4);
  int* cursor = (int*)alloc((size_t)N * 4);
  int* part = (int*)alloc(1024);
  int* csrsrc = (int*)alloc((size_t)E * 4);
  u16* CA = (u16*)alloc((size_t)NPAD * 1536 * 2);  // [H|T1|T2] Kpad=512
  u16* CB = (u16*)alloc((size_t)NPAD * 768 * 2);   // [H|T1|T2] Kpad=256
  u16* Wb = (u16*)alloc((size_t)1024 * 1536 * 2);
  (void)ws_size; (void)n_in; (void)out_size;

  // ---- graph normalization + CSR (by dst) ----
  k_zero_i32<<<NB, 256, 0, stream>>>(cnt, N);
  k_hist<<<EB, 256, 0, stream>>>(ei, cnt, E);
  k_dis<<<NB, 256, 0, stream>>>(cnt, dis, N);
  k_scan1<<<NB, 256, 0, stream>>>(cnt, part, N);
  k_scan2<<<1, 64, 0, stream>>>(part, NB, csroff, N, E);
  k_scan3<<<NB, 256, 0, stream>>>(cnt, part, csroff, cursor, N);
  k_scatter<<<EB, 256, 0, stream>>>(ei, cursor, csrsrc, E);

  const int RB = (N + 31) / 32;  // spmm row-blocks

  // ---- layer 1: 512 -> 250 (Kpad=512, ld 1536) ----
  k_convx<<<NPAD / 4, 256, 0, stream>>>(x, CA, N, NPAD);
  k_convw<<<256, 256, 0, stream>>>(w1, Wb, 512, 512, 250);
  spmm_c<<<dim3(RB, 16), 256, 0, stream>>>(CA, (const u16*)nullptr, CA + 512, 1536,
                                           csroff, csrsrc, dis, 1.f, N);
  spmm_c<<<dim3(RB, 16), 256, 0, stream>>>(CA + 512, CA, CA + 1024, 1536,
                                           csroff, csrsrc, dis, 2.f, N);
  gemm_k<u16><<<MT * 2, 256, 0, stream>>>(CA, 1536, Wb, 1536, b1,
                                          CB, 768, 1536, 250, N, 2);

  // ---- layer 2: 250 -> 500 (Kpad=256, ld 768) ----
  k_convw<<<512, 256, 0, stream>>>(w2, Wb, 250, 256, 500);
  spmm_c<<<dim3(RB, 8), 256, 0, stream>>>(CB, (const u16*)nullptr, CB + 256, 768,
                                          csroff, csrsrc, dis, 1.f, N);
  spmm_c<<<dim3(RB, 8), 256, 0, stream>>>(CB + 256, CB, CB + 512, 768,
                                          csroff, csrsrc, dis, 2.f, N);
  gemm_k<u16><<<MT * 4, 256, 0, stream>>>(CB, 768, Wb, 768, b2,
                                          CA, 1536, 768, 500, N, 4);

  // ---- layer 3: 500 -> 1000 (Kpad=512, ld 1536) ----
  k_convw<<<1024, 256, 0, stream>>>(w3, Wb, 500, 512, 1000);
  spmm_c<<<dim3(RB, 16), 256, 0, stream>>>(CA, (const u16*)nullptr, CA + 512, 1536,
                                           csroff, csrsrc, dis, 1.f, N);
  spmm_c<<<dim3(RB, 16), 256, 0, stream>>>(CA + 512, CA, CA + 1024, 1536,
                                           csroff, csrsrc, dis, 2.f, N);
  gemm_k<float><<<MT * 8, 256, 0, stream>>>(CA, 1536, Wb, 1536, b3,
                                            out, 1000, 1536, 1000, N, 8);
}

// Round 4
// 1775.047 us; speedup vs baseline: 1.5462x; 1.5462x over previous
//
#include <hip/hip_runtime.h>

// ChebConv(K=3) x3 on MI355X.  Round 4.
// SpMM: wave-per-row contiguous gather (round-1 form; chunking regressed: line
//       footprint 6.4MB > 4MB L2 -> thrash).  Layer 1 commuted through GEMM:
//       out1 = relu(U0 - U2 + Lhat(U1 + 2*Lhat(U2)) + b), Uk = X@Wk  -> L1
//       spmm width 256 instead of 512 (gather bytes halved).
// GEMM: 128x128 bf16 MFMA tile; bijective XCD swizzle, nt-minor; XOR LDS
//       swizzle (pre-swizzled global src + swizzled ds_read, linear dest).
// Arena: CA(154MB) aliases XB|U|P (dead before CA written).

typedef unsigned short u16;
typedef __attribute__((ext_vector_type(8))) short s16x8;
typedef __attribute__((ext_vector_type(4))) float f32x4;
typedef __attribute__((ext_vector_type(8))) unsigned short u16x8;
typedef __attribute__((ext_vector_type(4))) unsigned short u16x4;

__device__ __forceinline__ float b2f(u16 u) {
  union { unsigned int i; float f; } x; x.i = ((unsigned int)u) << 16; return x.f;
}
__device__ __forceinline__ u16 f2b(float f) {  // round-to-nearest-even
  union { float f; unsigned int i; } x; x.f = f;
  unsigned int r = x.i + 0x7fffu + ((x.i >> 16) & 1u);
  return (u16)(r >> 16);
}

typedef __attribute__((address_space(1))) unsigned int gu32_t;
typedef __attribute__((address_space(3))) unsigned int lu32_t;
__device__ __forceinline__ void gload16(const void* g, void* l) {
  __builtin_amdgcn_global_load_lds((const gu32_t*)g, (lu32_t*)l, 16, 0, 0);
}

// ----------------- CSR build -----------------
__global__ void k_zero_i32(int* p, int n) {
  int t = blockIdx.x * 256 + threadIdx.x;
  if (t < n) p[t] = 0;
}

__global__ void k_hist(const int* __restrict__ ei, int* __restrict__ cnt, int E) {
  int e = blockIdx.x * 256 + threadIdx.x;
  if (e < E) atomicAdd(&cnt[ei[E + e]], 1);  // ei[1][e] = dst
}

__global__ void k_dis(const int* __restrict__ cnt, float* __restrict__ dis, int N) {
  int t = blockIdx.x * 256 + threadIdx.x;
  if (t < N) dis[t] = cnt[t] > 0 ? rsqrtf((float)cnt[t]) : 0.f;
}

__global__ void k_scan1(const int* __restrict__ cnt, int* __restrict__ part, int N) {
  __shared__ int s[256];
  int t = threadIdx.x, idx = blockIdx.x * 256 + t;
  s[t] = idx < N ? cnt[idx] : 0;
  __syncthreads();
  for (int o = 128; o > 0; o >>= 1) {
    if (t < o) s[t] += s[t + o];
    __syncthreads();
  }
  if (t == 0) part[blockIdx.x] = s[0];
}

__global__ void k_scan2(int* part, int nb, int* csroff, int N, int E) {
  if (threadIdx.x == 0 && blockIdx.x == 0) {
    int run = 0;
    for (int b = 0; b < nb; ++b) { int v = part[b]; part[b] = run; run += v; }
    csroff[N] = E;
  }
}

__global__ void k_scan3(const int* __restrict__ cnt, const int* __restrict__ part,
                        int* __restrict__ csroff, int* __restrict__ cursor, int N) {
  __shared__ int s[256];
  int t = threadIdx.x, idx = blockIdx.x * 256 + t;
  int v = idx < N ? cnt[idx] : 0;
  s[t] = v;
  __syncthreads();
  for (int o = 1; o < 256; o <<= 1) {
    int add = t >= o ? s[t - o] : 0;
    __syncthreads();
    s[t] += add;
    __syncthreads();
  }
  if (idx < N) {
    int ex = part[blockIdx.x] + s[t] - v;
    csroff[idx] = ex;
    cursor[idx] = ex;
  }
}

__global__ void k_scatter(const int* __restrict__ ei, int* __restrict__ cursor,
                          int* __restrict__ csrsrc, int E) {
  int e = blockIdx.x * 256 + threadIdx.x;
  if (e >= E) return;
  int s = ei[e];          // src
  int d = ei[E + e];      // dst
  int pos = atomicAdd(&cursor[d], 1);
  csrsrc[pos] = s;
}

// ----------------- converts -----------------
__global__ void k_convx(const float* __restrict__ x, u16* __restrict__ C, int N, int NPAD) {
  int t = blockIdx.x * 256 + threadIdx.x;
  int row = t >> 6;
  if (row >= NPAD) return;
  int c0 = (t & 63) * 8;
  u16x8 o;
  if (row < N) {
    const float4* p = (const float4*)(x + (size_t)row * 512 + c0);
    float4 a = p[0], b = p[1];
    o[0] = f2b(a.x); o[1] = f2b(a.y); o[2] = f2b(a.z); o[3] = f2b(a.w);
    o[4] = f2b(b.x); o[5] = f2b(b.y); o[6] = f2b(b.z); o[7] = f2b(b.w);
  } else {
#pragma unroll
    for (int j = 0; j < 8; ++j) o[j] = 0;
  }
  *(u16x8*)(C + (size_t)row * 512 + c0) = o;
}

// kblk: Wb[n][ck*Kpad + kk] = W[ck][kk][n]  (B row n = output col n, K 3-blocked)
__global__ void k_convw_kblk(const float* __restrict__ W, u16* __restrict__ Wb,
                             int Fin, int Kpad, int Nout) {
  int n = blockIdx.x;
  int ldw = 3 * Kpad;
  for (int kk = threadIdx.x; kk < ldw; kk += 256) {
    int ck = kk / Kpad, k = kk - ck * Kpad;
    float v = (k < Fin && n < Nout) ? W[((size_t)ck * Fin + k) * Nout + n] : 0.f;
    Wb[(size_t)n * ldw + kk] = f2b(v);
  }
}

// nblk: Wb[ck*256 + j][k] = W[ck][k][j]  (N 3-blocked, plain K=512; for L1 U-GEMM)
__global__ void k_convw_nblk(const float* __restrict__ W, u16* __restrict__ Wb,
                             int Nout /*250*/) {
  int n = blockIdx.x;           // 0..767
  int ck = n >> 8, j = n & 255;
  for (int k = threadIdx.x; k < 512; k += 256) {
    float v = (j < Nout) ? W[((size_t)ck * 512 + k) * Nout + j] : 0.f;
    Wb[(size_t)n * 512 + k] = f2b(v);
  }
}

// ----------------- SpMM (wave-per-row contiguous gather) -----------------
template <int FV> struct UV;
template <> struct UV<8> { using T = u16x8; };
template <> struct UV<4> { using T = u16x4; };

// lap = Lhat(G)[r] = -dis[r]*sum_e dis[src]*G[src]  (+ -G[r] if isolated)
// MODE 0: O = lap                      (T1 pass)
// MODE 1: O = 2*lap - E0[r]            (T2 pass; E0 = H, lde)
// MODE 2: O = E0[r] + 2*lap            (P = U1 + 2*Lhat(U2); E0 = U1, lde)
// MODE 3: O = relu(E0[r]-E1[r]+lap+b)  (L1 out; E0=U0, E1=U2, lde; bias nreal)
template <int FV, int MODE>
__global__ __launch_bounds__(256) void spmm_k(
    const u16* __restrict__ G, int ldg,
    const u16* __restrict__ E0, const u16* __restrict__ E1, int lde,
    const float* __restrict__ bias, int nreal,
    u16* __restrict__ O, int ldo,
    const int* __restrict__ off, const int* __restrict__ srcs,
    const float* __restrict__ dis, int N) {
  using uvec = typename UV<FV>::T;
  const int r = blockIdx.x * 4 + (threadIdx.x >> 6);
  if (r >= N) return;
  const int c0 = (threadIdx.x & 63) * FV;
  const u16* __restrict__ Gc = G + c0;
  float acc[FV];
#pragma unroll
  for (int j = 0; j < FV; ++j) acc[j] = 0.f;
  int e = off[r];
  const int e1 = off[r + 1];
  for (; e + 2 <= e1; e += 2) {
    const int s0 = srcs[e], s1 = srcs[e + 1];
    const float w0 = dis[s0], w1 = dis[s1];
    const uvec v0 = *(const uvec*)(Gc + (size_t)s0 * ldg);
    const uvec v1 = *(const uvec*)(Gc + (size_t)s1 * ldg);
#pragma unroll
    for (int j = 0; j < FV; ++j) acc[j] += w0 * b2f(v0[j]) + w1 * b2f(v1[j]);
  }
  if (e < e1) {
    const int s0 = srcs[e];
    const float w0 = dis[s0];
    const uvec v0 = *(const uvec*)(Gc + (size_t)s0 * ldg);
#pragma unroll
    for (int j = 0; j < FV; ++j) acc[j] += w0 * b2f(v0[j]);
  }
  const float disr = dis[r];
  float lap[FV];
#pragma unroll
  for (int j = 0; j < FV; ++j) lap[j] = -disr * acc[j];
  if (disr == 0.f) {  // isolated node: Lhat row = -I row
    const uvec v = *(const uvec*)(Gc + (size_t)r * ldg);
#pragma unroll
    for (int j = 0; j < FV; ++j) lap[j] -= b2f(v[j]);
  }
  uvec o;
  if constexpr (MODE == 0) {
#pragma unroll
    for (int j = 0; j < FV; ++j) o[j] = f2b(lap[j]);
  } else if constexpr (MODE == 1) {
    const uvec h = *(const uvec*)(E0 + (size_t)r * lde + c0);
#pragma unroll
    for (int j = 0; j < FV; ++j) o[j] = f2b(2.f * lap[j] - b2f(h[j]));
  } else if constexpr (MODE == 2) {
    const uvec u1 = *(const uvec*)(E0 + (size_t)r * lde + c0);
#pragma unroll
    for (int j = 0; j < FV; ++j) o[j] = f2b(b2f(u1[j]) + 2.f * lap[j]);
  } else {  // MODE 3
    const uvec u0 = *(const uvec*)(E0 + (size_t)r * lde + c0);
    const uvec u2 = *(const uvec*)(E1 + (size_t)r * lde + c0);
#pragma unroll
    for (int j = 0; j < FV; ++j) {
      const int c = c0 + j;
      const float bv = (c < nreal) ? bias[c] : 0.f;
      float v = b2f(u0[j]) - b2f(u2[j]) + lap[j] + bv;
      o[j] = f2b(v > 0.f ? v : 0.f);
    }
  }
  *(uvec*)(O + (size_t)r * ldo + c0) = o;
}

// ----------------- GEMM: C = [relu](A @ B^T [+ bias]) -----------------
// A: [Mpad][lda] bf16 row-major; B: [Npad][ldb] bf16 (row n = output col n).
// 128x128 tile, BK=64, 4 waves (2x2), 16x16x32 MFMA, global_load_lds staging.
// 1-D grid, bijective XCD swizzle (m204), nt-minor.  XOR LDS swizzle.
// Col n is real iff (n & nmask) < nreal (handles 3-blocked pad structure).
template <typename OUTT, bool ACT>
__global__ __launch_bounds__(256) void gemm_k(
    const u16* __restrict__ A, int lda,
    const u16* __restrict__ B, int ldb,
    const float* __restrict__ bias,
    OUTT* __restrict__ C, int ldc,
    int K, int nmask, int nreal, int Nrows, int NT) {
  __shared__ u16 As[128 * 64];
  __shared__ u16 Bs[128 * 64];
  const int tid = threadIdx.x;
  const int w = tid >> 6, l = tid & 63;

  const int nwg = gridDim.x;
  const int q = nwg >> 3, r8 = nwg & 7;
  const int xcd = blockIdx.x & 7, idx = blockIdx.x >> 3;
  const int wg = (xcd < r8 ? xcd * (q + 1) : r8 * (q + 1) + (xcd - r8) * q) + idx;
  const int m0 = (wg / NT) * 128, n0 = (wg % NT) * 128;

  const int srow = w * 8 + (l >> 3);
  const int scol = ((l & 7) ^ (l >> 3)) * 8;  // pre-swizzled source granule
  const u16* ga = A + (size_t)m0 * lda + scol;
  const u16* gb = B + (size_t)n0 * ldb + scol;
  u16* lAs = &As[w * 512];
  u16* lBs = &Bs[w * 512];

  f32x4 acc[4][4];
#pragma unroll
  for (int m = 0; m < 4; ++m)
#pragma unroll
    for (int n = 0; n < 4; ++n) acc[m][n] = (f32x4){0.f, 0.f, 0.f, 0.f};

  const int wr = (w >> 1) * 64, wc = (w & 1) * 64;
  const int tr = l & 15, tg = l >> 4;
  const int rx = tr & 7;

  for (int k0 = 0; k0 < K; k0 += 64) {
    __syncthreads();
#pragma unroll
    for (int c = 0; c < 4; ++c) {
      gload16(ga + (size_t)(srow + c * 32) * lda + k0, lAs + c * 2048);
      gload16(gb + (size_t)(srow + c * 32) * ldb + k0, lBs + c * 2048);
    }
    __syncthreads();
#pragma unroll
    for (int kk = 0; kk < 64; kk += 32) {
      s16x8 af[4], bf[4];
#pragma unroll
      for (int m = 0; m < 4; ++m)
        af[m] = *(const s16x8*)&As[(wr + m * 16 + tr) * 64 + ((((kk >> 3) + tg) ^ rx) * 8)];
#pragma unroll
      for (int n = 0; n < 4; ++n)
        bf[n] = *(const s16x8*)&Bs[(wc + n * 16 + tr) * 64 + ((((kk >> 3) + tg) ^ rx) * 8)];
#pragma unroll
      for (int m = 0; m < 4; ++m)
#pragma unroll
        for (int n = 0; n < 4; ++n)
          acc[m][n] = __builtin_amdgcn_mfma_f32_16x16x32_bf16(af[m], bf[n], acc[m][n], 0, 0, 0);
    }
  }

  // epilogue; C/D layout: col = lane&15, row = (lane>>4)*4 + j
#pragma unroll
  for (int m = 0; m < 4; ++m) {
    const int gr0 = m0 + wr + m * 16 + tg * 4;
#pragma unroll
    for (int n = 0; n < 4; ++n) {
      const int gc = n0 + wc + n * 16 + tr;
      const bool cv = (gc & nmask) < nreal;
      const float bv = (ACT && cv) ? bias[gc] : 0.f;
#pragma unroll
      for (int j = 0; j < 4; ++j) {
        float v = acc[m][n][j] + bv;
        if (ACT) v = v > 0.f ? v : 0.f;
        if constexpr (sizeof(OUTT) == 2) {
          C[(size_t)(gr0 + j) * ldc + gc] = cv ? f2b(v) : (u16)0;
        } else {
          if (gr0 + j < Nrows && cv)
            C[(size_t)(gr0 + j) * ldc + gc] = v;
        }
      }
    }
  }
}

// ----------------- launch -----------------
extern "C" void kernel_launch(void* const* d_in, const int* in_sizes, int n_in,
                              void* d_out, int out_size, void* d_ws, size_t ws_size,
                              hipStream_t stream) {
  const float* x = (const float*)d_in[0];
  const int* ei = (const int*)d_in[1];
  const float* w1 = (const float*)d_in[2];
  const float* b1 = (const float*)d_in[3];
  const float* w2 = (const float*)d_in[4];
  const float* b2 = (const float*)d_in[5];
  const float* w3 = (const float*)d_in[6];
  const float* b3 = (const float*)d_in[7];
  float* out = (float*)d_out;

  const int N = in_sizes[0] / 512;      // 50000
  const int E = in_sizes[1] / 2;        // 1600000
  const int NPAD = ((N + 127) / 128) * 128;  // 50048
  const int NB = (N + 255) / 256;
  const int EB = (E + 255) / 256;
  const int MT = NPAD / 128;            // 391

  char* ws = (char*)d_ws;
  size_t o = 0;
  auto alloc = [&](size_t b) -> void* {
    void* p = ws + o;
    o = (o + b + 255) & ~(size_t)255;
    return p;
  };
  int* cnt = (int*)alloc((size_t)N * 4);
  float* dis = (float*)alloc((size_t)N * 4);
  int* csroff = (int*)alloc((size_t)(N + 1) * 4);
  int* cursor = (int*)alloc((size_t)N * 4);
  int* part = (int*)alloc(1024);
  int* csrsrc = (int*)alloc((size_t)E * 4);
  u16* CB = (u16*)alloc((size_t)NPAD * 768 * 2);   // [H|T1|T2] layer 2
  u16* CA = (u16*)alloc((size_t)NPAD * 1536 * 2);  // [H|T1|T2] layer 3; aliases:
  u16* XB = CA;                                    //   X bf16 [NPAD x 512]
  u16* U  = CA + (size_t)NPAD * 512;               //   U0|U1|U2 [NPAD x 768]
  u16* P  = U  + (size_t)NPAD * 768;               //   P [NPAD x 256]
  u16* Wb = (u16*)alloc((size_t)1024 * 1536 * 2);
  (void)ws_size; (void)n_in; (void)out_size;

  // ---- graph normalization + CSR (by dst) ----
  k_zero_i32<<<NB, 256, 0, stream>>>(cnt, N);
  k_hist<<<EB, 256, 0, stream>>>(ei, cnt, E);
  k_dis<<<NB, 256, 0, stream>>>(cnt, dis, N);
  k_scan1<<<NB, 256, 0, stream>>>(cnt, part, N);
  k_scan2<<<1, 64, 0, stream>>>(part, NB, csroff, N, E);
  k_scan3<<<NB, 256, 0, stream>>>(cnt, part, csroff, cursor, N);
  k_scatter<<<EB, 256, 0, stream>>>(ei, cursor, csrsrc, E);

  const int SG = (N + 3) / 4;  // 12500

  // ---- layer 1 (commuted): U = X @ [W0|W1|W2]; P = U1 + 2*Lhat(U2);
  //      H2 = relu(U0 - U2 + Lhat(P) + b1)  -> CB[:,0:256] ----
  k_convx<<<NPAD / 4, 256, 0, stream>>>(x, XB, N, NPAD);
  k_convw_nblk<<<768, 256, 0, stream>>>(w1, Wb, 250);
  gemm_k<u16, false><<<MT * 6, 256, 0, stream>>>(XB, 512, Wb, 512, nullptr,
                                                 U, 768, 512, 255, 250, N, 6);
  spmm_k<4, 2><<<SG, 256, 0, stream>>>(U + 512, 768, U + 256, (const u16*)nullptr, 768,
                                       nullptr, 0, P, 256, csroff, csrsrc, dis, N);
  spmm_k<4, 3><<<SG, 256, 0, stream>>>(P, 256, U, U + 512, 768,
                                       b1, 250, CB, 768, csroff, csrsrc, dis, N);

  // ---- layer 2 (original): T1 = Lhat(H); T2 = 2*Lhat(T1) - H; GEMM ----
  k_convw_kblk<<<512, 256, 0, stream>>>(w2, Wb, 250, 256, 500);
  spmm_k<4, 0><<<SG, 256, 0, stream>>>(CB, 768, (const u16*)nullptr, (const u16*)nullptr, 0,
                                       nullptr, 0, CB + 256, 768, csroff, csrsrc, dis, N);
  spmm_k<4, 1><<<SG, 256, 0, stream>>>(CB + 256, 768, CB, (const u16*)nullptr, 768,
                                       nullptr, 0, CB + 512, 768, csroff, csrsrc, dis, N);
  gemm_k<u16, true><<<MT * 4, 256, 0, stream>>>(CB, 768, Wb, 768, b2,
                                                CA, 1536, 768, 511, 500, N, 4);

  // ---- layer 3 (original) ----
  k_convw_kblk<<<1024, 256, 0, stream>>>(w3, Wb, 500, 512, 1000);
  spmm_k<8, 0><<<SG, 256, 0, stream>>>(CA, 1536, (const u16*)nullptr, (const u16*)nullptr, 0,
                                       nullptr, 0, CA + 512, 1536, csroff, csrsrc, dis, N);
  spmm_k<8, 1><<<SG, 256, 0, stream>>>(CA + 512, 1536, CA, (const u16*)nullptr, 1536,
                                       nullptr, 0, CA + 1024, 1536, csroff, csrsrc, dis, N);
  gemm_k<float, true><<<MT * 8, 256, 0, stream>>>(CA, 1536, Wb, 1536, b3,
                                                  out, 1000, 1536, 1023, 1000, N, 8);
}

// Round 5
// 1443.023 us; speedup vs baseline: 1.9019x; 1.2301x over previous
//
#include <hip/hip_runtime.h>

// ChebConv(K=3) x3 on MI355X.  Round 5.
// SpMM: wave-per-row contiguous gather of INT8 row-scaled tables (halves the
//       dominant gather bytes: 6.56 -> 3.28 GB).  qs[s] = dis[s]*scale[s]
//       folds dequant into the edge weight.  Layer 1 commuted through GEMM.
// GEMM: 128x128 bf16 MFMA tile; bijective XCD swizzle, nt-minor; XOR LDS
//       swizzle (verified r4: FETCH 622->177MB, bank conflicts 5.8e7->0).
// Q8 table aliases d_out (dead until final GEMM).

typedef unsigned short u16;
typedef __attribute__((ext_vector_type(8))) short s16x8;
typedef __attribute__((ext_vector_type(4))) float f32x4;
typedef __attribute__((ext_vector_type(8))) unsigned short u16x8;
typedef __attribute__((ext_vector_type(4))) unsigned short u16x4;
typedef __attribute__((ext_vector_type(8))) signed char s8x8;
typedef __attribute__((ext_vector_type(4))) signed char s8x4;

__device__ __forceinline__ float b2f(u16 u) {
  union { unsigned int i; float f; } x; x.i = ((unsigned int)u) << 16; return x.f;
}
__device__ __forceinline__ u16 f2b(float f) {  // round-to-nearest-even
  union { float f; unsigned int i; } x; x.f = f;
  unsigned int r = x.i + 0x7fffu + ((x.i >> 16) & 1u);
  return (u16)(r >> 16);
}

typedef __attribute__((address_space(1))) unsigned int gu32_t;
typedef __attribute__((address_space(3))) unsigned int lu32_t;
__device__ __forceinline__ void gload16(const void* g, void* l) {
  __builtin_amdgcn_global_load_lds((const gu32_t*)g, (lu32_t*)l, 16, 0, 0);
}

// ----------------- CSR build -----------------
__global__ void k_zero_i32(int* p, int n) {
  int t = blockIdx.x * 256 + threadIdx.x;
  if (t < n) p[t] = 0;
}

__global__ void k_hist(const int* __restrict__ ei, int* __restrict__ cnt, int E) {
  int e = blockIdx.x * 256 + threadIdx.x;
  if (e < E) atomicAdd(&cnt[ei[E + e]], 1);  // ei[1][e] = dst
}

__global__ void k_dis(const int* __restrict__ cnt, float* __restrict__ dis, int N) {
  int t = blockIdx.x * 256 + threadIdx.x;
  if (t < N) dis[t] = cnt[t] > 0 ? rsqrtf((float)cnt[t]) : 0.f;
}

__global__ void k_scan1(const int* __restrict__ cnt, int* __restrict__ part, int N) {
  __shared__ int s[256];
  int t = threadIdx.x, idx = blockIdx.x * 256 + t;
  s[t] = idx < N ? cnt[idx] : 0;
  __syncthreads();
  for (int o = 128; o > 0; o >>= 1) {
    if (t < o) s[t] += s[t + o];
    __syncthreads();
  }
  if (t == 0) part[blockIdx.x] = s[0];
}

__global__ void k_scan2(int* part, int nb, int* csroff, int N, int E) {
  if (threadIdx.x == 0 && blockIdx.x == 0) {
    int run = 0;
    for (int b = 0; b < nb; ++b) { int v = part[b]; part[b] = run; run += v; }
    csroff[N] = E;
  }
}

__global__ void k_scan3(const int* __restrict__ cnt, const int* __restrict__ part,
                        int* __restrict__ csroff, int* __restrict__ cursor, int N) {
  __shared__ int s[256];
  int t = threadIdx.x, idx = blockIdx.x * 256 + t;
  int v = idx < N ? cnt[idx] : 0;
  s[t] = v;
  __syncthreads();
  for (int o = 1; o < 256; o <<= 1) {
    int add = t >= o ? s[t - o] : 0;
    __syncthreads();
    s[t] += add;
    __syncthreads();
  }
  if (idx < N) {
    int ex = part[blockIdx.x] + s[t] - v;
    csroff[idx] = ex;
    cursor[idx] = ex;
  }
}

__global__ void k_scatter(const int* __restrict__ ei, int* __restrict__ cursor,
                          int* __restrict__ csrsrc, int E) {
  int e = blockIdx.x * 256 + threadIdx.x;
  if (e >= E) return;
  int s = ei[e];          // src
  int d = ei[E + e];      // dst
  int pos = atomicAdd(&cursor[d], 1);
  csrsrc[pos] = s;
}

// ----------------- converts -----------------
__global__ void k_convx(const float* __restrict__ x, u16* __restrict__ C, int N, int NPAD) {
  int t = blockIdx.x * 256 + threadIdx.x;
  int row = t >> 6;
  if (row >= NPAD) return;
  int c0 = (t & 63) * 8;
  u16x8 o;
  if (row < N) {
    const float4* p = (const float4*)(x + (size_t)row * 512 + c0);
    float4 a = p[0], b = p[1];
    o[0] = f2b(a.x); o[1] = f2b(a.y); o[2] = f2b(a.z); o[3] = f2b(a.w);
    o[4] = f2b(b.x); o[5] = f2b(b.y); o[6] = f2b(b.z); o[7] = f2b(b.w);
  } else {
#pragma unroll
    for (int j = 0; j < 8; ++j) o[j] = 0;
  }
  *(u16x8*)(C + (size_t)row * 512 + c0) = o;
}

// kblk: Wb[n][ck*Kpad + kk] = W[ck][kk][n]
__global__ void k_convw_kblk(const float* __restrict__ W, u16* __restrict__ Wb,
                             int Fin, int Kpad, int Nout) {
  int n = blockIdx.x;
  int ldw = 3 * Kpad;
  for (int kk = threadIdx.x; kk < ldw; kk += 256) {
    int ck = kk / Kpad, k = kk - ck * Kpad;
    float v = (k < Fin && n < Nout) ? W[((size_t)ck * Fin + k) * Nout + n] : 0.f;
    Wb[(size_t)n * ldw + kk] = f2b(v);
  }
}

// nblk: Wb[ck*256 + j][k] = W[ck][k][j]  (for L1 U-GEMM)
__global__ void k_convw_nblk(const float* __restrict__ W, u16* __restrict__ Wb,
                             int Nout /*250*/) {
  int n = blockIdx.x;           // 0..767
  int ck = n >> 8, j = n & 255;
  for (int k = threadIdx.x; k < 512; k += 256) {
    float v = (j < Nout) ? W[((size_t)ck * 512 + k) * Nout + j] : 0.f;
    Wb[(size_t)n * 512 + k] = f2b(v);
  }
}

// ----------------- int8 row-scaled quantize -----------------
// 4 rows/block (wave per row).  Q[r] = round(T[r]/scale), scale = absmax/127.
// qs[r] = dis[r]*scale[r] (edge weight), sc[r] = scale[r] (diag path).
template <int FV>
__global__ __launch_bounds__(256) void k_quant(
    const u16* __restrict__ T, int ldt, signed char* __restrict__ Q, int ldq,
    const float* __restrict__ dis, float* __restrict__ qs, float* __restrict__ sc,
    int N) {
  using uvec = typename
      __hip_internal::conditional<FV == 8, u16x8, u16x4>::type;
  using qvec = typename
      __hip_internal::conditional<FV == 8, s8x8, s8x4>::type;
  const int r = blockIdx.x * 4 + (threadIdx.x >> 6);
  if (r >= N) return;
  const int l = threadIdx.x & 63, c0 = l * FV;
  const uvec v = *(const uvec*)(T + (size_t)r * ldt + c0);
  float f[FV];
  float m = 0.f;
#pragma unroll
  for (int j = 0; j < FV; ++j) { f[j] = b2f(v[j]); m = fmaxf(m, fabsf(f[j])); }
#pragma unroll
  for (int o = 32; o > 0; o >>= 1) m = fmaxf(m, __shfl_xor(m, o, 64));
  const float inv = m > 0.f ? 127.f / m : 0.f;
  qvec q;
#pragma unroll
  for (int j = 0; j < FV; ++j) q[j] = (signed char)(int)rintf(f[j] * inv);
  *(qvec*)(Q + (size_t)r * ldq + c0) = q;
  if (l == 0) {
    const float s = m > 0.f ? m * (1.f / 127.f) : 0.f;
    sc[r] = s;
    qs[r] = dis[r] * s;
  }
}

// ----------------- SpMM (wave-per-row int8 gather) -----------------
// lap = Lhat(G)[r] = -dis[r]*sum_e qs[src]*Q[src]  (+ -sc[r]*Q[r] if isolated)
// MODE 0: O = lap                      (T1 pass)
// MODE 1: O = 2*lap - E0[r]            (T2 pass)
// MODE 2: O = E0[r] + 2*lap            (P = U1 + 2*Lhat(U2))
// MODE 3: O = relu(E0[r]-E1[r]+lap+b)  (L1 out)
template <int FV, int MODE>
__global__ __launch_bounds__(256) void spmm_q(
    const signed char* __restrict__ Q, int ldq,
    const float* __restrict__ qs, const float* __restrict__ sc,
    const u16* __restrict__ E0, const u16* __restrict__ E1, int lde,
    const float* __restrict__ bias, int nreal,
    u16* __restrict__ O, int ldo,
    const int* __restrict__ off, const int* __restrict__ srcs,
    const float* __restrict__ dis, int N) {
  using uvec = typename
      __hip_internal::conditional<FV == 8, u16x8, u16x4>::type;
  using qvec = typename
      __hip_internal::conditional<FV == 8, s8x8, s8x4>::type;
  const int r = blockIdx.x * 4 + (threadIdx.x >> 6);
  if (r >= N) return;
  const int c0 = (threadIdx.x & 63) * FV;
  const signed char* __restrict__ Qc = Q + c0;
  float acc[FV];
#pragma unroll
  for (int j = 0; j < FV; ++j) acc[j] = 0.f;
  int e = off[r];
  const int e1 = off[r + 1];
  for (; e + 4 <= e1; e += 4) {  // unroll x4: 4 outstanding gathers
    const int s0 = srcs[e], s1 = srcs[e + 1], s2 = srcs[e + 2], s3 = srcs[e + 3];
    const float w0 = qs[s0], w1 = qs[s1], w2 = qs[s2], w3 = qs[s3];
    const qvec v0 = *(const qvec*)(Qc + (size_t)s0 * ldq);
    const qvec v1 = *(const qvec*)(Qc + (size_t)s1 * ldq);
    const qvec v2 = *(const qvec*)(Qc + (size_t)s2 * ldq);
    const qvec v3 = *(const qvec*)(Qc + (size_t)s3 * ldq);
#pragma unroll
    for (int j = 0; j < FV; ++j)
      acc[j] += w0 * (float)v0[j] + w1 * (float)v1[j] +
                w2 * (float)v2[j] + w3 * (float)v3[j];
  }
  for (; e < e1; ++e) {
    const int s0 = srcs[e];
    const float w0 = qs[s0];
    const qvec v0 = *(const qvec*)(Qc + (size_t)s0 * ldq);
#pragma unroll
    for (int j = 0; j < FV; ++j) acc[j] += w0 * (float)v0[j];
  }
  const float disr = dis[r];
  float lap[FV];
#pragma unroll
  for (int j = 0; j < FV; ++j) lap[j] = -disr * acc[j];
  if (disr == 0.f) {  // isolated node: Lhat row = -I row
    const float s = sc[r];
    const qvec v = *(const qvec*)(Qc + (size_t)r * ldq);
#pragma unroll
    for (int j = 0; j < FV; ++j) lap[j] -= s * (float)v[j];
  }
  uvec o;
  if constexpr (MODE == 0) {
#pragma unroll
    for (int j = 0; j < FV; ++j) o[j] = f2b(lap[j]);
  } else if constexpr (MODE == 1) {
    const uvec h = *(const uvec*)(E0 + (size_t)r * lde + c0);
#pragma unroll
    for (int j = 0; j < FV; ++j) o[j] = f2b(2.f * lap[j] - b2f(h[j]));
  } else if constexpr (MODE == 2) {
    const uvec u1 = *(const uvec*)(E0 + (size_t)r * lde + c0);
#pragma unroll
    for (int j = 0; j < FV; ++j) o[j] = f2b(b2f(u1[j]) + 2.f * lap[j]);
  } else {  // MODE 3
    const uvec u0 = *(const uvec*)(E0 + (size_t)r * lde + c0);
    const uvec u2 = *(const uvec*)(E1 + (size_t)r * lde + c0);
#pragma unroll
    for (int j = 0; j < FV; ++j) {
      const int c = c0 + j;
      const float bv = (c < nreal) ? bias[c] : 0.f;
      float v = b2f(u0[j]) - b2f(u2[j]) + lap[j] + bv;
      o[j] = f2b(v > 0.f ? v : 0.f);
    }
  }
  *(uvec*)(O + (size_t)r * ldo + c0) = o;
}

// ----------------- GEMM: C = [relu](A @ B^T [+ bias]) -----------------
template <typename OUTT, bool ACT>
__global__ __launch_bounds__(256) void gemm_k(
    const u16* __restrict__ A, int lda,
    const u16* __restrict__ B, int ldb,
    const float* __restrict__ bias,
    OUTT* __restrict__ C, int ldc,
    int K, int nmask, int nreal, int Nrows, int NT) {
  __shared__ u16 As[128 * 64];
  __shared__ u16 Bs[128 * 64];
  const int tid = threadIdx.x;
  const int w = tid >> 6, l = tid & 63;

  const int nwg = gridDim.x;
  const int q = nwg >> 3, r8 = nwg & 7;
  const int xcd = blockIdx.x & 7, idx = blockIdx.x >> 3;
  const int wg = (xcd < r8 ? xcd * (q + 1) : r8 * (q + 1) + (xcd - r8) * q) + idx;
  const int m0 = (wg / NT) * 128, n0 = (wg % NT) * 128;

  const int srow = w * 8 + (l >> 3);
  const int scol = ((l & 7) ^ (l >> 3)) * 8;  // pre-swizzled source granule
  const u16* ga = A + (size_t)m0 * lda + scol;
  const u16* gb = B + (size_t)n0 * ldb + scol;
  u16* lAs = &As[w * 512];
  u16* lBs = &Bs[w * 512];

  f32x4 acc[4][4];
#pragma unroll
  for (int m = 0; m < 4; ++m)
#pragma unroll
    for (int n = 0; n < 4; ++n) acc[m][n] = (f32x4){0.f, 0.f, 0.f, 0.f};

  const int wr = (w >> 1) * 64, wc = (w & 1) * 64;
  const int tr = l & 15, tg = l >> 4;
  const int rx = tr & 7;

  for (int k0 = 0; k0 < K; k0 += 64) {
    __syncthreads();
#pragma unroll
    for (int c = 0; c < 4; ++c) {
      gload16(ga + (size_t)(srow + c * 32) * lda + k0, lAs + c * 2048);
      gload16(gb + (size_t)(srow + c * 32) * ldb + k0, lBs + c * 2048);
    }
    __syncthreads();
#pragma unroll
    for (int kk = 0; kk < 64; kk += 32) {
      s16x8 af[4], bf[4];
#pragma unroll
      for (int m = 0; m < 4; ++m)
        af[m] = *(const s16x8*)&As[(wr + m * 16 + tr) * 64 + ((((kk >> 3) + tg) ^ rx) * 8)];
#pragma unroll
      for (int n = 0; n < 4; ++n)
        bf[n] = *(const s16x8*)&Bs[(wc + n * 16 + tr) * 64 + ((((kk >> 3) + tg) ^ rx) * 8)];
#pragma unroll
      for (int m = 0; m < 4; ++m)
#pragma unroll
        for (int n = 0; n < 4; ++n)
          acc[m][n] = __builtin_amdgcn_mfma_f32_16x16x32_bf16(af[m], bf[n], acc[m][n], 0, 0, 0);
    }
  }

  // epilogue; C/D layout: col = lane&15, row = (lane>>4)*4 + j
#pragma unroll
  for (int m = 0; m < 4; ++m) {
    const int gr0 = m0 + wr + m * 16 + tg * 4;
#pragma unroll
    for (int n = 0; n < 4; ++n) {
      const int gc = n0 + wc + n * 16 + tr;
      const bool cv = (gc & nmask) < nreal;
      const float bv = (ACT && cv) ? bias[gc] : 0.f;
#pragma unroll
      for (int j = 0; j < 4; ++j) {
        float v = acc[m][n][j] + bv;
        if (ACT) v = v > 0.f ? v : 0.f;
        if constexpr (sizeof(OUTT) == 2) {
          C[(size_t)(gr0 + j) * ldc + gc] = cv ? f2b(v) : (u16)0;
        } else {
          if (gr0 + j < Nrows && cv)
            C[(size_t)(gr0 + j) * ldc + gc] = v;
        }
      }
    }
  }
}

// ----------------- launch -----------------
extern "C" void kernel_launch(void* const* d_in, const int* in_sizes, int n_in,
                              void* d_out, int out_size, void* d_ws, size_t ws_size,
                              hipStream_t stream) {
  const float* x = (const float*)d_in[0];
  const int* ei = (const int*)d_in[1];
  const float* w1 = (const float*)d_in[2];
  const float* b1 = (const float*)d_in[3];
  const float* w2 = (const float*)d_in[4];
  const float* b2 = (const float*)d_in[5];
  const float* w3 = (const float*)d_in[6];
  const float* b3 = (const float*)d_in[7];
  float* out = (float*)d_out;

  const int N = in_sizes[0] / 512;      // 50000
  const int E = in_sizes[1] / 2;        // 1600000
  const int NPAD = ((N + 127) / 128) * 128;  // 50048
  const int NB = (N + 255) / 256;
  const int EB = (E + 255) / 256;
  const int MT = NPAD / 128;            // 391

  char* ws = (char*)d_ws;
  size_t o = 0;
  auto alloc = [&](size_t b) -> void* {
    void* p = ws + o;
    o = (o + b + 255) & ~(size_t)255;
    return p;
  };
  int* cnt = (int*)alloc((size_t)N * 4);
  float* dis = (float*)alloc((size_t)N * 4);
  int* csroff = (int*)alloc((size_t)(N + 1) * 4);
  int* cursor = (int*)alloc((size_t)N * 4);
  int* part = (int*)alloc(1024);
  float* qs = (float*)alloc((size_t)N * 4);
  float* sc = (float*)alloc((size_t)N * 4);
  int* csrsrc = (int*)alloc((size_t)E * 4);
  u16* CB = (u16*)alloc((size_t)NPAD * 768 * 2);   // [H|T1|T2] layer 2
  u16* CA = (u16*)alloc((size_t)NPAD * 1536 * 2);  // [H|T1|T2] layer 3; aliases:
  u16* XB = CA;                                    //   X bf16 [NPAD x 512]
  u16* U  = CA + (size_t)NPAD * 512;               //   U0|U1|U2 [NPAD x 768]
  u16* P  = U  + (size_t)NPAD * 768;               //   P [NPAD x 256]
  u16* Wb = (u16*)alloc((size_t)1024 * 1536 * 2);
  signed char* Q8 = (signed char*)d_out;  // int8 gather table; dead before final GEMM
  (void)ws_size; (void)n_in; (void)out_size;

  // ---- graph normalization + CSR (by dst) ----
  k_zero_i32<<<NB, 256, 0, stream>>>(cnt, N);
  k_hist<<<EB, 256, 0, stream>>>(ei, cnt, E);
  k_dis<<<NB, 256, 0, stream>>>(cnt, dis, N);
  k_scan1<<<NB, 256, 0, stream>>>(cnt, part, N);
  k_scan2<<<1, 64, 0, stream>>>(part, NB, csroff, N, E);
  k_scan3<<<NB, 256, 0, stream>>>(cnt, part, csroff, cursor, N);
  k_scatter<<<EB, 256, 0, stream>>>(ei, cursor, csrsrc, E);

  const int SG = (N + 3) / 4;  // 12500

  // ---- layer 1 (commuted): U = X @ [W0|W1|W2]; P = U1 + 2*Lhat(U2);
  //      H2 = relu(U0 - U2 + Lhat(P) + b1)  -> CB[:,0:256] ----
  k_convx<<<NPAD / 4, 256, 0, stream>>>(x, XB, N, NPAD);
  k_convw_nblk<<<768, 256, 0, stream>>>(w1, Wb, 250);
  gemm_k<u16, false><<<MT * 6, 256, 0, stream>>>(XB, 512, Wb, 512, nullptr,
                                                 U, 768, 512, 255, 250, N, 6);
  k_quant<4><<<SG, 256, 0, stream>>>(U + 512, 768, Q8, 256, dis, qs, sc, N);
  spmm_q<4, 2><<<SG, 256, 0, stream>>>(Q8, 256, qs, sc, U + 256, (const u16*)nullptr, 768,
                                       nullptr, 0, P, 256, csroff, csrsrc, dis, N);
  k_quant<4><<<SG, 256, 0, stream>>>(P, 256, Q8, 256, dis, qs, sc, N);
  spmm_q<4, 3><<<SG, 256, 0, stream>>>(Q8, 256, qs, sc, U, U + 512, 768,
                                       b1, 250, CB, 768, csroff, csrsrc, dis, N);

  // ---- layer 2: T1 = Lhat(H); T2 = 2*Lhat(T1) - H; GEMM ----
  k_convw_kblk<<<512, 256, 0, stream>>>(w2, Wb, 250, 256, 500);
  k_quant<4><<<SG, 256, 0, stream>>>(CB, 768, Q8, 256, dis, qs, sc, N);
  spmm_q<4, 0><<<SG, 256, 0, stream>>>(Q8, 256, qs, sc, (const u16*)nullptr, (const u16*)nullptr, 0,
                                       nullptr, 0, CB + 256, 768, csroff, csrsrc, dis, N);
  k_quant<4><<<SG, 256, 0, stream>>>(CB + 256, 768, Q8, 256, dis, qs, sc, N);
  spmm_q<4, 1><<<SG, 256, 0, stream>>>(Q8, 256, qs, sc, CB, (const u16*)nullptr, 768,
                                       nullptr, 0, CB + 512, 768, csroff, csrsrc, dis, N);
  gemm_k<u16, true><<<MT * 4, 256, 0, stream>>>(CB, 768, Wb, 768, b2,
                                                CA, 1536, 768, 511, 500, N, 4);

  // ---- layer 3 ----
  k_convw_kblk<<<1024, 256, 0, stream>>>(w3, Wb, 500, 512, 1000);
  k_quant<8><<<SG, 256, 0, stream>>>(CA, 1536, Q8, 512, dis, qs, sc, N);
  spmm_q<8, 0><<<SG, 256, 0, stream>>>(Q8, 512, qs, sc, (const u16*)nullptr, (const u16*)nullptr, 0,
                                       nullptr, 0, CA + 512, 1536, csroff, csrsrc, dis, N);
  k_quant<8><<<SG, 256, 0, stream>>>(CA + 512, 1536, Q8, 512, dis, qs, sc, N);
  spmm_q<8, 1><<<SG, 256, 0, stream>>>(Q8, 512, qs, sc, CA, (const u16*)nullptr, 1536,
                                       nullptr, 0, CA + 1024, 1536, csroff, csrsrc, dis, N);
  gemm_k<float, true><<<MT * 8, 256, 0, stream>>>(CA, 1536, Wb, 1536, b3,
                                                  out, 1000, 1536, 1023, 1000, N, 8);
}

// Round 6
// 1433.605 us; speedup vs baseline: 1.9144x; 1.0066x over previous
//
#include <hip/hip_runtime.h>

// ChebConv(K=3) x3 on MI355X.  Round 6.
// SpMM: int8 row-scaled wave-per-row gather (r5, verified: absmax unchanged).
// GEMM: NEW 256x256 8-phase schedule (T2+T3+T4+T5): 8 waves (2Mx4N), BK=64,
//       2-dbuf 128KB LDS, counted vmcnt(4) at phases 4/8 only, setprio around
//       MFMA clusters, XOR LDS swizzle, bijective XCD swizzle, nt-minor.
//       Stage slots: ph1=B(2i+1), ph4=A(2i+2), ph5=B(2i+2), ph8=A(2i+3).
//       Proof: each half-tile staged >= 3 phases + one vmcnt(4)+barrier before
//       first read; restage >= 1 barrier after last read of its region.

typedef unsigned short u16;
typedef __attribute__((ext_vector_type(8))) short s16x8;
typedef __attribute__((ext_vector_type(4))) float f32x4;
typedef __attribute__((ext_vector_type(8))) unsigned short u16x8;
typedef __attribute__((ext_vector_type(4))) unsigned short u16x4;
typedef __attribute__((ext_vector_type(8))) signed char s8x8;
typedef __attribute__((ext_vector_type(4))) signed char s8x4;

__device__ __forceinline__ float b2f(u16 u) {
  union { unsigned int i; float f; } x; x.i = ((unsigned int)u) << 16; return x.f;
}
__device__ __forceinline__ u16 f2b(float f) {  // round-to-nearest-even
  union { float f; unsigned int i; } x; x.f = f;
  unsigned int r = x.i + 0x7fffu + ((x.i >> 16) & 1u);
  return (u16)(r >> 16);
}

typedef __attribute__((address_space(1))) unsigned int gu32_t;
typedef __attribute__((address_space(3))) unsigned int lu32_t;
__device__ __forceinline__ void gload16(const void* g, void* l) {
  __builtin_amdgcn_global_load_lds((const gu32_t*)g, (lu32_t*)l, 16, 0, 0);
}

// ----------------- CSR build -----------------
__global__ void k_zero_i32(int* p, int n) {
  int t = blockIdx.x * 256 + threadIdx.x;
  if (t < n) p[t] = 0;
}

__global__ void k_hist(const int* __restrict__ ei, int* __restrict__ cnt, int E) {
  int e = blockIdx.x * 256 + threadIdx.x;
  if (e < E) atomicAdd(&cnt[ei[E + e]], 1);  // ei[1][e] = dst
}

__global__ void k_dis(const int* __restrict__ cnt, float* __restrict__ dis, int N) {
  int t = blockIdx.x * 256 + threadIdx.x;
  if (t < N) dis[t] = cnt[t] > 0 ? rsqrtf((float)cnt[t]) : 0.f;
}

__global__ void k_scan1(const int* __restrict__ cnt, int* __restrict__ part, int N) {
  __shared__ int s[256];
  int t = threadIdx.x, idx = blockIdx.x * 256 + t;
  s[t] = idx < N ? cnt[idx] : 0;
  __syncthreads();
  for (int o = 128; o > 0; o >>= 1) {
    if (t < o) s[t] += s[t + o];
    __syncthreads();
  }
  if (t == 0) part[blockIdx.x] = s[0];
}

__global__ void k_scan2(int* part, int nb, int* csroff, int N, int E) {
  if (threadIdx.x == 0 && blockIdx.x == 0) {
    int run = 0;
    for (int b = 0; b < nb; ++b) { int v = part[b]; part[b] = run; run += v; }
    csroff[N] = E;
  }
}

__global__ void k_scan3(const int* __restrict__ cnt, const int* __restrict__ part,
                        int* __restrict__ csroff, int* __restrict__ cursor, int N) {
  __shared__ int s[256];
  int t = threadIdx.x, idx = blockIdx.x * 256 + t;
  int v = idx < N ? cnt[idx] : 0;
  s[t] = v;
  __syncthreads();
  for (int o = 1; o < 256; o <<= 1) {
    int add = t >= o ? s[t - o] : 0;
    __syncthreads();
    s[t] += add;
    __syncthreads();
  }
  if (idx < N) {
    int ex = part[blockIdx.x] + s[t] - v;
    csroff[idx] = ex;
    cursor[idx] = ex;
  }
}

__global__ void k_scatter(const int* __restrict__ ei, int* __restrict__ cursor,
                          int* __restrict__ csrsrc, int E) {
  int e = blockIdx.x * 256 + threadIdx.x;
  if (e >= E) return;
  int s = ei[e];          // src
  int d = ei[E + e];      // dst
  int pos = atomicAdd(&cursor[d], 1);
  csrsrc[pos] = s;
}

// ----------------- converts -----------------
__global__ void k_convx(const float* __restrict__ x, u16* __restrict__ C, int N, int NPAD) {
  int t = blockIdx.x * 256 + threadIdx.x;
  int row = t >> 6;
  if (row >= NPAD) return;
  int c0 = (t & 63) * 8;
  u16x8 o;
  if (row < N) {
    const float4* p = (const float4*)(x + (size_t)row * 512 + c0);
    float4 a = p[0], b = p[1];
    o[0] = f2b(a.x); o[1] = f2b(a.y); o[2] = f2b(a.z); o[3] = f2b(a.w);
    o[4] = f2b(b.x); o[5] = f2b(b.y); o[6] = f2b(b.z); o[7] = f2b(b.w);
  } else {
#pragma unroll
    for (int j = 0; j < 8; ++j) o[j] = 0;
  }
  *(u16x8*)(C + (size_t)row * 512 + c0) = o;
}

// kblk: Wb[n][ck*Kpad + kk] = W[ck][kk][n]
__global__ void k_convw_kblk(const float* __restrict__ W, u16* __restrict__ Wb,
                             int Fin, int Kpad, int Nout) {
  int n = blockIdx.x;
  int ldw = 3 * Kpad;
  for (int kk = threadIdx.x; kk < ldw; kk += 256) {
    int ck = kk / Kpad, k = kk - ck * Kpad;
    float v = (k < Fin && n < Nout) ? W[((size_t)ck * Fin + k) * Nout + n] : 0.f;
    Wb[(size_t)n * ldw + kk] = f2b(v);
  }
}

// nblk: Wb[ck*256 + j][k] = W[ck][k][j]  (for L1 U-GEMM)
__global__ void k_convw_nblk(const float* __restrict__ W, u16* __restrict__ Wb,
                             int Nout /*250*/) {
  int n = blockIdx.x;           // 0..767
  int ck = n >> 8, j = n & 255;
  for (int k = threadIdx.x; k < 512; k += 256) {
    float v = (j < Nout) ? W[((size_t)ck * 512 + k) * Nout + j] : 0.f;
    Wb[(size_t)n * 512 + k] = f2b(v);
  }
}

// ----------------- int8 row-scaled quantize -----------------
template <int FV>
__global__ __launch_bounds__(256) void k_quant(
    const u16* __restrict__ T, int ldt, signed char* __restrict__ Q, int ldq,
    const float* __restrict__ dis, float* __restrict__ qs, float* __restrict__ sc,
    int N) {
  using uvec = typename
      __hip_internal::conditional<FV == 8, u16x8, u16x4>::type;
  using qvec = typename
      __hip_internal::conditional<FV == 8, s8x8, s8x4>::type;
  const int r = blockIdx.x * 4 + (threadIdx.x >> 6);
  if (r >= N) return;
  const int l = threadIdx.x & 63, c0 = l * FV;
  const uvec v = *(const uvec*)(T + (size_t)r * ldt + c0);
  float f[FV];
  float m = 0.f;
#pragma unroll
  for (int j = 0; j < FV; ++j) { f[j] = b2f(v[j]); m = fmaxf(m, fabsf(f[j])); }
#pragma unroll
  for (int o = 32; o > 0; o >>= 1) m = fmaxf(m, __shfl_xor(m, o, 64));
  const float inv = m > 0.f ? 127.f / m : 0.f;
  qvec q;
#pragma unroll
  for (int j = 0; j < FV; ++j) q[j] = (signed char)(int)rintf(f[j] * inv);
  *(qvec*)(Q + (size_t)r * ldq + c0) = q;
  if (l == 0) {
    const float s = m > 0.f ? m * (1.f / 127.f) : 0.f;
    sc[r] = s;
    qs[r] = dis[r] * s;
  }
}

// ----------------- SpMM (wave-per-row int8 gather) -----------------
template <int FV, int MODE>
__global__ __launch_bounds__(256) void spmm_q(
    const signed char* __restrict__ Q, int ldq,
    const float* __restrict__ qs, const float* __restrict__ sc,
    const u16* __restrict__ E0, const u16* __restrict__ E1, int lde,
    const float* __restrict__ bias, int nreal,
    u16* __restrict__ O, int ldo,
    const int* __restrict__ off, const int* __restrict__ srcs,
    const float* __restrict__ dis, int N) {
  using uvec = typename
      __hip_internal::conditional<FV == 8, u16x8, u16x4>::type;
  using qvec = typename
      __hip_internal::conditional<FV == 8, s8x8, s8x4>::type;
  const int r = blockIdx.x * 4 + (threadIdx.x >> 6);
  if (r >= N) return;
  const int c0 = (threadIdx.x & 63) * FV;
  const signed char* __restrict__ Qc = Q + c0;
  float acc[FV];
#pragma unroll
  for (int j = 0; j < FV; ++j) acc[j] = 0.f;
  int e = off[r];
  const int e1 = off[r + 1];
  for (; e + 4 <= e1; e += 4) {
    const int s0 = srcs[e], s1 = srcs[e + 1], s2 = srcs[e + 2], s3 = srcs[e + 3];
    const float w0 = qs[s0], w1 = qs[s1], w2 = qs[s2], w3 = qs[s3];
    const qvec v0 = *(const qvec*)(Qc + (size_t)s0 * ldq);
    const qvec v1 = *(const qvec*)(Qc + (size_t)s1 * ldq);
    const qvec v2 = *(const qvec*)(Qc + (size_t)s2 * ldq);
    const qvec v3 = *(const qvec*)(Qc + (size_t)s3 * ldq);
#pragma unroll
    for (int j = 0; j < FV; ++j)
      acc[j] += w0 * (float)v0[j] + w1 * (float)v1[j] +
                w2 * (float)v2[j] + w3 * (float)v3[j];
  }
  for (; e < e1; ++e) {
    const int s0 = srcs[e];
    const float w0 = qs[s0];
    const qvec v0 = *(const qvec*)(Qc + (size_t)s0 * ldq);
#pragma unroll
    for (int j = 0; j < FV; ++j) acc[j] += w0 * (float)v0[j];
  }
  const float disr = dis[r];
  float lap[FV];
#pragma unroll
  for (int j = 0; j < FV; ++j) lap[j] = -disr * acc[j];
  if (disr == 0.f) {  // isolated node: Lhat row = -I row
    const float s = sc[r];
    const qvec v = *(const qvec*)(Qc + (size_t)r * ldq);
#pragma unroll
    for (int j = 0; j < FV; ++j) lap[j] -= s * (float)v[j];
  }
  uvec o;
  if constexpr (MODE == 0) {
#pragma unroll
    for (int j = 0; j < FV; ++j) o[j] = f2b(lap[j]);
  } else if constexpr (MODE == 1) {
    const uvec h = *(const uvec*)(E0 + (size_t)r * lde + c0);
#pragma unroll
    for (int j = 0; j < FV; ++j) o[j] = f2b(2.f * lap[j] - b2f(h[j]));
  } else if constexpr (MODE == 2) {
    const uvec u1 = *(const uvec*)(E0 + (size_t)r * lde + c0);
#pragma unroll
    for (int j = 0; j < FV; ++j) o[j] = f2b(b2f(u1[j]) + 2.f * lap[j]);
  } else {  // MODE 3
    const uvec u0 = *(const uvec*)(E0 + (size_t)r * lde + c0);
    const uvec u2 = *(const uvec*)(E1 + (size_t)r * lde + c0);
#pragma unroll
    for (int j = 0; j < FV; ++j) {
      const int c = c0 + j;
      const float bv = (c < nreal) ? bias[c] : 0.f;
      float v = b2f(u0[j]) - b2f(u2[j]) + lap[j] + bv;
      o[j] = f2b(v > 0.f ? v : 0.f);
    }
  }
  *(uvec*)(O + (size_t)r * ldo + c0) = o;
}

// ----------------- GEMM 256x256 8-phase: C = [relu](A @ B^T [+ bias]) -----
// A: [Mpad2][lda] bf16; B: [Nrows_b][ldb] bf16 (row n = output col n).
// 512 thr = 8 waves (2M x 4N); per-wave C 128x64; acc[8][4] f32x4.
// LDS: sh[buf][mat][half][128*64] = 128 KiB.  K-tiles even count (K%128==0).
template <typename OUTT, bool ACT>
__global__ __launch_bounds__(512, 2) void gemm8(
    const u16* __restrict__ A, int lda,
    const u16* __restrict__ B, int ldb,
    const float* __restrict__ bias,
    OUTT* __restrict__ C, int ldc,
    int K, int nmask, int nreal, int Nrows, int NT) {
  __shared__ u16 sh[2][2][2][8192];
  const int tid = threadIdx.x;
  const int wv = tid >> 6, ln = tid & 63;

  const int nwg = gridDim.x;
  const int qq = nwg >> 3, r8 = nwg & 7;
  const int xcd = blockIdx.x & 7, bidx = blockIdx.x >> 3;
  const int wg = (xcd < r8 ? xcd * (qq + 1) : r8 * (qq + 1) + (xcd - r8) * qq) + bidx;
  const int m0 = (wg / NT) * 256, n0 = (wg % NT) * 256;

  const int wm = wv >> 2, wn = wv & 3;
  const int tr = ln & 15, tg = ln >> 4, rx = tr & 7;

  // staging source: thread covers 16B; row = tid>>3 (+64 for round 2),
  // source granule pre-swizzled so LDS stays linear (rule #21).
  const int srow = tid >> 3;
  const int sgr = (tid & 7) ^ (srow & 7);
  const u16* gA = A + (size_t)(m0 + srow) * lda + sgr * 8;
  const u16* gB = B + (size_t)(n0 + srow) * ldb + sgr * 8;

  f32x4 acc[8][4];
#pragma unroll
  for (int mf = 0; mf < 8; ++mf)
#pragma unroll
    for (int nf = 0; nf < 4; ++nf) acc[mf][nf] = (f32x4){0.f, 0.f, 0.f, 0.f};
  s16x8 fa[8], fb0[4], fb1[4];

  auto SA = [&](int b, int kt, int h) {  // stage A half h of K-tile kt
    const u16* s = gA + (size_t)h * 128 * lda + kt * 64;
    u16* d = &sh[b][0][h][wv * 512];     // wave-uniform base; HW adds lane*16B
    gload16(s, d);
    gload16(s + (size_t)64 * lda, d + 4096);
  };
  auto SB = [&](int b, int kt, int h) {
    const u16* s = gB + (size_t)h * 128 * ldb + kt * 64;
    u16* d = &sh[b][1][h][wv * 512];
    gload16(s, d);
    gload16(s + (size_t)64 * ldb, d + 4096);
  };
  auto LDA_ = [&](int b, int mh) {  // 8 x ds_read_b128
    const u16* base = &sh[b][0][wm][0];
#pragma unroll
    for (int mf = 0; mf < 4; ++mf)
#pragma unroll
      for (int kx = 0; kx < 2; ++kx) {
        const int row = mh * 64 + mf * 16 + tr;
        fa[mf * 2 + kx] = *(const s16x8*)&base[row * 64 + (((kx * 4 + tg) ^ rx) * 8)];
      }
  };
  auto LDB_ = [&](int b, int nh, s16x8* fb) {  // 4 x ds_read_b128
    const u16* base = &sh[b][1][wn >> 1][0];
#pragma unroll
    for (int nf = 0; nf < 2; ++nf)
#pragma unroll
      for (int kx = 0; kx < 2; ++kx) {
        const int row = (wn & 1) * 64 + (nh * 2 + nf) * 16 + tr;
        fb[nf * 2 + kx] = *(const s16x8*)&base[row * 64 + (((kx * 4 + tg) ^ rx) * 8)];
      }
  };
  auto MM = [&](int mh, int nh, const s16x8* fb) {  // 16 MFMA quadrant
    __builtin_amdgcn_s_setprio(1);
#pragma unroll
    for (int kx = 0; kx < 2; ++kx)
#pragma unroll
      for (int mf = 0; mf < 4; ++mf)
#pragma unroll
        for (int nf = 0; nf < 2; ++nf)
          acc[mh * 4 + mf][nh * 2 + nf] = __builtin_amdgcn_mfma_f32_16x16x32_bf16(
              fa[mf * 2 + kx], fb[nf * 2 + kx], acc[mh * 4 + mf][nh * 2 + nf], 0, 0, 0);
    __builtin_amdgcn_s_setprio(0);
  };
#define BAR8() { __builtin_amdgcn_s_barrier(); asm volatile("" ::: "memory"); }
#define VC4() asm volatile("s_waitcnt vmcnt(4)" ::: "memory")

  const int nkt = K >> 6;
  // prologue: tile0 all 4 halves + tile1 A-halves; wait first 8 loads.
  SA(0, 0, 0); SA(0, 0, 1); SB(0, 0, 0); SB(0, 0, 1);
  SA(1, 1, 0); SA(1, 1, 1);
  VC4();
  BAR8();
  for (int i = 0; i < (nkt >> 1); ++i) {
    const int t1 = 2 * i + 1, t2 = 2 * i + 2, t3 = 2 * i + 3;
    // ph1: reads buf0 A-mh0 + B-nh0; stage B(t1)->buf1
    LDA_(0, 0); LDB_(0, 0, fb0);
    SB(1, t1, 0); SB(1, t1, 1);
    BAR8(); MM(0, 0, fb0); BAR8();
    // ph2
    LDB_(0, 1, fb1);
    BAR8(); MM(0, 1, fb1); BAR8();
    // ph3
    LDA_(0, 1);
    BAR8(); MM(1, 1, fb1); BAR8();
    // ph4: stage A(t2)->buf0; counted wait
    if (t2 < nkt) { SA(0, t2, 0); SA(0, t2, 1); }
    BAR8(); MM(1, 0, fb0);
    VC4();
    BAR8();
    // ph5: reads buf1; stage B(t2)->buf0
    LDA_(1, 0); LDB_(1, 0, fb0);
    if (t2 < nkt) { SB(0, t2, 0); SB(0, t2, 1); }
    BAR8(); MM(0, 0, fb0); BAR8();
    // ph6
    LDB_(1, 1, fb1);
    BAR8(); MM(0, 1, fb1); BAR8();
    // ph7
    LDA_(1, 1);
    BAR8(); MM(1, 1, fb1); BAR8();
    // ph8: stage A(t3)->buf1; counted wait
    if (t3 < nkt) { SA(1, t3, 0); SA(1, t3, 1); }
    BAR8(); MM(1, 0, fb0);
    VC4();
    BAR8();
  }
#undef BAR8
#undef VC4

  // epilogue; C/D layout: col = lane&15, row = (lane>>4)*4 + j
#pragma unroll
  for (int mf = 0; mf < 8; ++mf) {
    const int gr0 = m0 + wm * 128 + mf * 16 + tg * 4;
#pragma unroll
    for (int nf = 0; nf < 4; ++nf) {
      const int gc = n0 + wn * 64 + nf * 16 + tr;
      const bool cv = (gc & nmask) < nreal;
      const float bv = (ACT && cv) ? bias[gc] : 0.f;
#pragma unroll
      for (int j = 0; j < 4; ++j) {
        float v = acc[mf][nf][j] + bv;
        if (ACT) v = v > 0.f ? v : 0.f;
        if constexpr (sizeof(OUTT) == 2) {
          C[(size_t)(gr0 + j) * ldc + gc] = cv ? f2b(v) : (u16)0;
        } else {
          if (gr0 + j < Nrows && cv)
            C[(size_t)(gr0 + j) * ldc + gc] = v;
        }
      }
    }
  }
}

// ----------------- launch -----------------
extern "C" void kernel_launch(void* const* d_in, const int* in_sizes, int n_in,
                              void* d_out, int out_size, void* d_ws, size_t ws_size,
                              hipStream_t stream) {
  const float* x = (const float*)d_in[0];
  const int* ei = (const int*)d_in[1];
  const float* w1 = (const float*)d_in[2];
  const float* b1 = (const float*)d_in[3];
  const float* w2 = (const float*)d_in[4];
  const float* b2 = (const float*)d_in[5];
  const float* w3 = (const float*)d_in[6];
  const float* b3 = (const float*)d_in[7];
  float* out = (float*)d_out;

  const int N = in_sizes[0] / 512;      // 50000
  const int E = in_sizes[1] / 2;        // 1600000
  const int NPAD2 = ((N + 255) / 256) * 256;  // 50176 (256-tile GEMM)
  const int NB = (N + 255) / 256;
  const int EB = (E + 255) / 256;
  const int MT2 = NPAD2 / 256;          // 196

  char* ws = (char*)d_ws;
  size_t o = 0;
  auto alloc = [&](size_t b) -> void* {
    void* p = ws + o;
    o = (o + b + 255) & ~(size_t)255;
    return p;
  };
  int* cnt = (int*)alloc((size_t)N * 4);
  float* dis = (float*)alloc((size_t)N * 4);
  int* csroff = (int*)alloc((size_t)(N + 1) * 4);
  int* cursor = (int*)alloc((size_t)N * 4);
  int* part = (int*)alloc(1024);
  float* qs = (float*)alloc((size_t)N * 4);
  float* sc = (float*)alloc((size_t)N * 4);
  int* csrsrc = (int*)alloc((size_t)E * 4);
  u16* CB = (u16*)alloc((size_t)NPAD2 * 768 * 2);   // [H|T1|T2] layer 2
  u16* CA = (u16*)alloc((size_t)NPAD2 * 1536 * 2);  // [H|T1|T2] layer 3; aliases:
  u16* XB = CA;                                     //   X bf16 [NPAD2 x 512]
  u16* U  = CA + (size_t)NPAD2 * 512;               //   U0|U1|U2 [NPAD2 x 768]
  u16* P  = U  + (size_t)NPAD2 * 768;               //   P [NPAD2 x 256]
  u16* Wb = (u16*)alloc((size_t)1024 * 1536 * 2);
  signed char* Q8 = (signed char*)d_out;  // int8 gather table; dead before final GEMM
  (void)ws_size; (void)n_in; (void)out_size;

  // ---- graph normalization + CSR (by dst) ----
  k_zero_i32<<<NB, 256, 0, stream>>>(cnt, N);
  k_hist<<<EB, 256, 0, stream>>>(ei, cnt, E);
  k_dis<<<NB, 256, 0, stream>>>(cnt, dis, N);
  k_scan1<<<NB, 256, 0, stream>>>(cnt, part, N);
  k_scan2<<<1, 64, 0, stream>>>(part, NB, csroff, N, E);
  k_scan3<<<NB, 256, 0, stream>>>(cnt, part, csroff, cursor, N);
  k_scatter<<<EB, 256, 0, stream>>>(ei, cursor, csrsrc, E);

  const int SG = (N + 3) / 4;  // 12500

  // ---- layer 1 (commuted): U = X @ [W0|W1|W2]; P = U1 + 2*Lhat(U2);
  //      H2 = relu(U0 - U2 + Lhat(P) + b1)  -> CB[:,0:256] ----
  k_convx<<<NPAD2 / 4, 256, 0, stream>>>(x, XB, N, NPAD2);
  k_convw_nblk<<<768, 256, 0, stream>>>(w1, Wb, 250);
  gemm8<u16, false><<<MT2 * 3, 512, 0, stream>>>(XB, 512, Wb, 512, nullptr,
                                                 U, 768, 512, 255, 250, N, 3);
  k_quant<4><<<SG, 256, 0, stream>>>(U + 512, 768, Q8, 256, dis, qs, sc, N);
  spmm_q<4, 2><<<SG, 256, 0, stream>>>(Q8, 256, qs, sc, U + 256, (const u16*)nullptr, 768,
                                       nullptr, 0, P, 256, csroff, csrsrc, dis, N);
  k_quant<4><<<SG, 256, 0, stream>>>(P, 256, Q8, 256, dis, qs, sc, N);
  spmm_q<4, 3><<<SG, 256, 0, stream>>>(Q8, 256, qs, sc, U, U + 512, 768,
                                       b1, 250, CB, 768, csroff, csrsrc, dis, N);

  // ---- layer 2: T1 = Lhat(H); T2 = 2*Lhat(T1) - H; GEMM ----
  k_convw_kblk<<<512, 256, 0, stream>>>(w2, Wb, 250, 256, 500);
  k_quant<4><<<SG, 256, 0, stream>>>(CB, 768, Q8, 256, dis, qs, sc, N);
  spmm_q<4, 0><<<SG, 256, 0, stream>>>(Q8, 256, qs, sc, (const u16*)nullptr, (const u16*)nullptr, 0,
                                       nullptr, 0, CB + 256, 768, csroff, csrsrc, dis, N);
  k_quant<4><<<SG, 256, 0, stream>>>(CB + 256, 768, Q8, 256, dis, qs, sc, N);
  spmm_q<4, 1><<<SG, 256, 0, stream>>>(Q8, 256, qs, sc, CB, (const u16*)nullptr, 768,
                                       nullptr, 0, CB + 512, 768, csroff, csrsrc, dis, N);
  gemm8<u16, true><<<MT2 * 2, 512, 0, stream>>>(CB, 768, Wb, 768, b2,
                                                CA, 1536, 768, 511, 500, N, 2);

  // ---- layer 3 ----
  k_convw_kblk<<<1024, 256, 0, stream>>>(w3, Wb, 500, 512, 1000);
  k_quant<8><<<SG, 256, 0, stream>>>(CA, 1536, Q8, 512, dis, qs, sc, N);
  spmm_q<8, 0><<<SG, 256, 0, stream>>>(Q8, 512, qs, sc, (const u16*)nullptr, (const u16*)nullptr, 0,
                                       nullptr, 0, CA + 512, 1536, csroff, csrsrc, dis, N);
  k_quant<8><<<SG, 256, 0, stream>>>(CA + 512, 1536, Q8, 512, dis, qs, sc, N);
  spmm_q<8, 1><<<SG, 256, 0, stream>>>(Q8, 512, qs, sc, CA, (const u16*)nullptr, 1536,
                                       nullptr, 0, CA + 1024, 1536, csroff, csrsrc, dis, N);
  gemm8<float, true><<<MT2 * 4, 512, 0, stream>>>(CA, 1536, Wb, 1536, b3,
                                                  out, 1000, 1536, 1023, 1000, N, 4);
}